// Round 1
// baseline (211.771 us; speedup 1.0000x reference)
//
#include <hip/hip_runtime.h>
#include <math.h>

#define SS 64
#define BB 32
#define DD 586
#define DE 583      // emb columns
#define U1 114      // length after conv1+pool1
#define U2 38       // after pool2
#define T3 36       // conv3 out length
#define NTOK 18752  // B*D elements per s
#define SQD 24.207436873820409f  // sqrt(586)

// Fully fused: one block per s (64 blocks, 256 threads). No workspace.
// Per-s BatchNorm stats are over that s's own 32 rows x 586 cols -> block-local.
// Deferred affine: conv(al*x+de) = al*conv(x) + de*wsum, so conv runs on RAW
// x staged once in LDS; the 4 BN layers collapse to one (al, de) pair.
__global__ __launch_bounds__(256) void k_fused(
    const int* __restrict__ tokens, const float* __restrict__ emb,
    const float* __restrict__ pos, const float* __restrict__ gamma,
    const float* __restrict__ beta, const float* __restrict__ w1,
    const float* __restrict__ b1, const float* __restrict__ w2,
    const float* __restrict__ b2, const float* __restrict__ w3,
    const float* __restrict__ b3, const float* __restrict__ wl,
    const float* __restrict__ bl, float* __restrict__ out)
{
  const int s = blockIdx.x;
  const int tid = threadIdx.x;
  __shared__ float xs[BB*DD];     // 75.0 KB raw x tile (32 rows)
  __shared__ float o2[16*U1];     // conv1+pool1 output
  __shared__ float p2[16*U2];
  __shared__ float o4[8*U2];
  __shared__ float o5[32*T3];
  __shared__ float wlb[128*37];   // +1 pad: conflict-free
  __shared__ float blb[128];
  __shared__ float wsumb[16];
  __shared__ float sAl, sDe;
  __shared__ double rs[BB], rq[BB];
  __shared__ int stok[BB];

  if (tid < BB) stok[tid] = tokens[s*BB + tid];
  for (int idx = tid; idx < 128*36; idx += 256) {
    int v = idx / 36, t = idx - v*36;
    wlb[v*37 + t] = wl[idx];
  }
  if (tid < 128) blb[tid] = bl[tid];
  // wsum[o] = sum over c,k of w1[o][c][k] (544 contiguous floats)
  {
    const int o = tid >> 4, i = tid & 15;
    float acc = 0.f;
    for (int j = i; j < BB*17; j += 16) acc += w1[o*BB*17 + j];
    for (int off = 8; off > 0; off >>= 1) acc += __shfl_down(acc, off, 16);
    if (i == 0) wsumb[o] = acc;
  }
  __syncthreads();

  // gather: 4 passes of 8 rows x 32 lanes; per-row sum/sq from the SAME
  // staged tile (single gather). Each thread's elements belong to ONE row.
  {
    const int rr0 = tid >> 5, l = tid & 31;
    for (int it = 0; it < 4; ++it) {
      const int rr = rr0 + 8*it;
      const float* row = emb + (size_t)stok[rr]*DE;
      double sum = 0.0, sq = 0.0;
      #pragma unroll
      for (int j = 0; j < 19; ++j) {
        int d = l + 32*j;
        if (d < DD) {
          float v = (d < DE) ? row[d] * SQD
                             : pos[(s*BB + rr)*3 + (d - DE)];
          xs[rr*DD + d] = v;
          sum += v; sq += (double)v*v;
        }
      }
      for (int off = 16; off > 0; off >>= 1) {  // width-32 tree per row
        sum += __shfl_down(sum, off, 32);
        sq  += __shfl_down(sq, off, 32);
      }
      if (l == 0) { rs[rr] = sum; rq[rr] = sq; }
    }
  }
  __syncthreads();

  // deterministic stats reduce (32 doubles, fixed tree) -> al, de
  if (tid < 32) {
    double sm = rs[tid], qq = rq[tid];
    for (int off = 16; off > 0; off >>= 1) {
      sm += __shfl_down(sm, off, 32);
      qq += __shfl_down(qq, off, 32);
    }
    if (tid == 0) {
      double m0d = sm / (double)NTOK;
      float m0 = (float)m0d;
      float v0 = (float)(qq / (double)NTOK - m0d*m0d);
      float a = 1.0f;
      for (int l2 = 0; l2 < 4; ++l2) {
        float r = 1.0f / sqrtf(a*a*v0 + 1e-5f);
        a = gamma[l2*SS + s] * r * a;
      }
      sAl = a;
      sDe = beta[3*SS + s] - a*m0;
    }
  }
  __syncthreads();
  const float al = sAl, de = sDe;

  // conv1 + avgpool(5), all 32 input channels, affine applied inline.
  // out_raw[o,u] = 0.2 * sum_{c,k} w1[o,c,k] * xw[c,k],
  //   xw[c,k] = sum_{m=k..k+4} x[c,5u+m]   (k=0..16)
  {
    const int up = tid & 127;
    const int oh = __builtin_amdgcn_readfirstlane(tid >> 7);  // wave-uniform
    const int u  = (up < U1) ? up : (U1 - 1);
    float acc[8] = {0,0,0,0,0,0,0,0};
    for (int cc = 0; cc < BB; ++cc) {
      const float* xr = &xs[cc*DD + 5*u];   // stride-5 lanes: 2-way max, free
      float xv[21];
      #pragma unroll
      for (int m = 0; m < 21; ++m) xv[m] = xr[m];
      float xw[17];
      #pragma unroll
      for (int k = 0; k < 17; ++k)
        xw[k] = ((xv[k] + xv[k+1]) + (xv[k+2] + xv[k+3])) + xv[k+4];
      #pragma unroll
      for (int j = 0; j < 8; ++j) {
        // wave-uniform base -> scalar loads, no LDS traffic for weights
        const float* wj = w1 + ((size_t)(oh*8 + j)*BB + cc)*17;
        float a = 0.f;
        #pragma unroll
        for (int k = 0; k < 17; ++k) a += xw[k] * wj[k];
        acc[j] += a;
      }
    }
    if (up < U1) {
      #pragma unroll
      for (int j = 0; j < 8; ++j) {
        int o = oh*8 + j;
        o2[o*U1 + up] = al*(acc[j]*0.2f) + de*wsumb[o] + b1[o];
      }
    }
  }
  __syncthreads();

  for (int i2 = tid; i2 < 16*U2; i2 += 256) {   // pool2: 608 > 256
    int o = i2 / U2, v = i2 - o*U2;
    p2[i2] = (o2[o*U1 + 3*v] + o2[o*U1 + 3*v+1] + o2[o*U1 + 3*v+2]) * (1.f/3.f);
  }
  __syncthreads();
  for (int i2 = tid; i2 < 8*U2; i2 += 256) {    // conv2 (1x1): 304 > 256
    int p = i2 / U2, v = i2 - p*U2;
    float acc = b2[p];
    #pragma unroll
    for (int o = 0; o < 16; ++o) acc += p2[o*U2 + v] * w2[p*16 + o];
    o4[i2] = acc;
  }
  __syncthreads();
  for (int i2 = tid; i2 < 32*T3; i2 += 256) {   // conv3 (k=3): 1152 > 256
    int q = i2 / T3, t = i2 - q*T3;
    float acc = b3[q];
    #pragma unroll
    for (int p = 0; p < 8; ++p) {
      acc += o4[p*U2 + t    ] * w3[(q*8+p)*3 + 0]
           + o4[p*U2 + t + 1] * w3[(q*8+p)*3 + 1]
           + o4[p*U2 + t + 2] * w3[(q*8+p)*3 + 2];
    }
    o5[i2] = acc;
  }
  __syncthreads();

  // dense 36->128 + argmax: q = tid>>3, vs = tid&7; v = vs + 8*i ascending
  // per thread; (max,min-idx) merge preserves first-max tie-break.
  const int q = tid >> 3, vs = tid & 7;
  float best = -1e30f; int bidx = 0;
  const float* orow = &o5[q*T3];
  for (int i = 0; i < 16; ++i) {
    int v = vs + 8*i;
    float acc = blb[v];
    const float* wr = &wlb[v*37];
    #pragma unroll
    for (int t = 0; t < 36; ++t) acc += orow[t] * wr[t];
    if (acc > best) { best = acc; bidx = v; }
  }
  #pragma unroll
  for (int off = 1; off < 8; off <<= 1) {
    float ov = __shfl_xor(best, off);
    int oi = __shfl_xor(bidx, off);
    if (ov > best || (ov == best && oi < bidx)) { best = ov; bidx = oi; }
  }
  if (vs == 0) out[s*BB + q] = (float)bidx;
}

extern "C" void kernel_launch(void* const* d_in, const int* in_sizes, int n_in,
                              void* d_out, int out_size, void* d_ws, size_t ws_size,
                              hipStream_t stream)
{
  const int*   tokens = (const int*)  d_in[0];
  const float* emb    = (const float*)d_in[1];
  const float* pos    = (const float*)d_in[2];
  const float* gamma  = (const float*)d_in[3];
  const float* beta   = (const float*)d_in[4];
  const float* w1     = (const float*)d_in[5];
  const float* b1     = (const float*)d_in[6];
  const float* w2     = (const float*)d_in[7];
  const float* b2     = (const float*)d_in[8];
  const float* w3     = (const float*)d_in[9];
  const float* b3     = (const float*)d_in[10];
  const float* wl     = (const float*)d_in[11];
  const float* bl     = (const float*)d_in[12];
  float* out = (float*)d_out;
  (void)d_ws; (void)ws_size;  // workspace intentionally untouched

  k_fused<<<dim3(SS), dim3(256), 0, stream>>>(
      tokens, emb, pos, gamma, beta, w1, b1, w2, b2, w3, b3, wl, bl, out);
}

// Round 2
// 194.249 us; speedup vs baseline: 1.0902x; 1.0902x over previous
//
#include <hip/hip_runtime.h>
#include <math.h>

#define SS 64
#define BB 32
#define DD 586
#define DE 583      // emb columns
#define U1 114      // length after conv1+pool1
#define U2 38       // after pool2
#define T3 36       // conv3 out length
#define NTOK 18752  // B*D elements per s
#define NSTAT (SS*BB)
#define SQD 24.207436873820409f  // sqrt(586)

// ws layout:
//   double rowsumd[2048]; double rowsqd[2048];
//   float  part[4][64][16][114];   // raw conv1+pool1 partials (no affine)

// ---- K1: gather once -> row stats + raw fused conv1+avgpool(5) ----
// grid (s=64, g=4); 256 threads.
// Deferred affine: conv(al*x+de) = al*conv(x) + de*wsum, so conv runs on RAW
// x and stats are computed from the SAME staged tile (single gather).
// Conv identity: out_raw[o,u] = 0.2 * sum_{c,k} w1[o,c,k] * xw[c,k],
//   xw[c,k] = sum_{m=k..k+4} x[c,5u+m]   (k=0..16)
__global__ __launch_bounds__(256) void k_main(
    const int* __restrict__ tokens, const float* __restrict__ emb,
    const float* __restrict__ pos, const float* __restrict__ w1,
    double* __restrict__ rowsumd, double* __restrict__ rowsqd,
    float* __restrict__ part)
{
  const int s = blockIdx.x, g = blockIdx.y;
  const int tid = threadIdx.x;
  __shared__ float xs[8*DD];
  __shared__ int stok[8];
  if (tid < 8) stok[tid] = tokens[s*BB + g*8 + tid];
  __syncthreads();
  // gather: row rr = tid>>5 (8 rows x 32 lanes), d = (tid&31) + 32j.
  // Each thread's elements belong to ONE row -> clean per-row reduction.
  {
    const int rr = tid >> 5, l = tid & 31;
    const float* row = emb + (size_t)stok[rr]*DE;
    double sum = 0.0, sq = 0.0;
    #pragma unroll
    for (int j = 0; j < 19; ++j) {
      int d = l + 32*j;
      if (d < DD) {
        float v = (d < DE) ? row[d] * SQD
                           : pos[(s*BB + g*8 + rr)*3 + (d - DE)];
        xs[rr*DD + d] = v;
        sum += v; sq += (double)v*v;
      }
    }
    // width-32 tree: lanes 0-31 / 32-63 reduce their own row independently
    for (int off = 16; off > 0; off >>= 1) {
      sum += __shfl_down(sum, off, 32);
      sq  += __shfl_down(sq, off, 32);
    }
    if (l == 0) {
      rowsumd[s*BB + g*8 + rr] = sum;
      rowsqd [s*BB + g*8 + rr] = sq;
    }
  }
  __syncthreads();
  // conv: up=tid&127 -> u, oh=tid>>7 -> o in [8oh, 8oh+8)
  const int up = tid & 127;
  const int oh = __builtin_amdgcn_readfirstlane(tid >> 7);  // wave-uniform
  const int u  = (up < U1) ? up : (U1 - 1);
  float acc[8] = {0,0,0,0,0,0,0,0};
  for (int cc = 0; cc < 8; ++cc) {
    const float* xr = &xs[cc*DD + 5*u];   // stride-5 lanes: conflict-free
    float xv[21];
    #pragma unroll
    for (int m = 0; m < 21; ++m) xv[m] = xr[m];
    float xw[17];
    #pragma unroll
    for (int k = 0; k < 17; ++k)
      xw[k] = ((xv[k] + xv[k+1]) + (xv[k+2] + xv[k+3])) + xv[k+4];
    #pragma unroll
    for (int j = 0; j < 8; ++j) {
      // wave-uniform base -> scalar loads, no LDS traffic for weights
      const float* wj = w1 + ((size_t)(oh*8 + j)*BB + (g*8 + cc))*17;
      float a = 0.f;
      #pragma unroll
      for (int k = 0; k < 17; ++k) a += xw[k] * wj[k];
      acc[j] += a;
    }
  }
  if (up < U1) {
    float* pb = part + ((size_t)(g*SS + s)*16 + oh*8)*U1 + up;
    #pragma unroll
    for (int j = 0; j < 8; ++j) pb[j*U1] = acc[j] * 0.2f;  // coalesced
  }
}

// ---- K2: stats -> affine assembly, pool2, conv2, conv3, dense, argmax ----
__global__ __launch_bounds__(256) void k_tail(
    const double* __restrict__ rowsumd, const double* __restrict__ rowsqd,
    const float* __restrict__ gamma, const float* __restrict__ beta,
    const float* __restrict__ part, const float* __restrict__ w1,
    const float* __restrict__ b1, const float* __restrict__ w2,
    const float* __restrict__ b2, const float* __restrict__ w3,
    const float* __restrict__ b3, const float* __restrict__ wl,
    const float* __restrict__ bl, float* __restrict__ out)
{
  const int s = blockIdx.x, tid = threadIdx.x;
  __shared__ float o2[16*U1];
  __shared__ float p2[16*U2];
  __shared__ float o4[8*U2];
  __shared__ float o5[32*T3];
  __shared__ float wlb[128*37];   // +1 pad: conflict-free
  __shared__ float blb[128];
  __shared__ float wsumb[16];
  __shared__ float sAl, sDe;
  for (int idx = tid; idx < 128*36; idx += 256) {
    int v = idx / 36, t = idx - v*36;
    wlb[v*37 + t] = wl[idx];
  }
  if (tid < 128) blb[tid] = bl[tid];
  // wsum[o] = sum over c,k of w1[o][c][k] = sum of 544 contiguous floats
  {
    const int o = tid >> 4, i = tid & 15;
    float acc = 0.f;
    for (int j = i; j < BB*17; j += 16) acc += w1[o*BB*17 + j];
    for (int off = 8; off > 0; off >>= 1) acc += __shfl_down(acc, off, 16);
    if (i == 0) wsumb[o] = acc;
  }
  // deterministic stats reduce (32 doubles, fixed tree) -> al, de
  if (tid < 32) {
    double sm = rowsumd[s*BB + tid], qq = rowsqd[s*BB + tid];
    for (int off = 16; off > 0; off >>= 1) {
      sm += __shfl_down(sm, off, 32);
      qq += __shfl_down(qq, off, 32);
    }
    if (tid == 0) {
      double m0d = sm / (double)NTOK;
      float m0 = (float)m0d;
      float v0 = (float)(qq / (double)NTOK - m0d*m0d);
      float a = 1.0f;
      for (int l = 0; l < 4; ++l) {
        float r = 1.0f / sqrtf(a*a*v0 + 1e-5f);
        a = gamma[l*SS + s] * r * a;
      }
      sAl = a;
      sDe = beta[3*SS + s] - a*m0;
    }
  }
  __syncthreads();
  const float al = sAl, de = sDe;
  for (int idx = tid; idx < 16*U1; idx += 256) {
    int o = idx / U1;
    float psum = part[(size_t)(0*SS + s)*16*U1 + idx]
               + part[(size_t)(1*SS + s)*16*U1 + idx]
               + part[(size_t)(2*SS + s)*16*U1 + idx]
               + part[(size_t)(3*SS + s)*16*U1 + idx];
    o2[idx] = al*psum + de*wsumb[o] + b1[o];
  }
  __syncthreads();
  for (int i2 = tid; i2 < 16*U2; i2 += 256) {   // 608 > 256: loop required
    int o = i2 / U2, v = i2 - o*U2;
    p2[i2] = (o2[o*U1 + 3*v] + o2[o*U1 + 3*v+1] + o2[o*U1 + 3*v+2]) * (1.f/3.f);
  }
  __syncthreads();
  for (int i2 = tid; i2 < 8*U2; i2 += 256) {    // 304 > 256: loop required
    int p = i2 / U2, v = i2 - p*U2;
    float acc = b2[p];
    #pragma unroll
    for (int o = 0; o < 16; ++o) acc += p2[o*U2 + v] * w2[p*16 + o];
    o4[i2] = acc;
  }
  __syncthreads();
  for (int i2 = tid; i2 < 32*T3; i2 += 256) {   // 1152 > 256: loop required
    int q = i2 / T3, t = i2 - q*T3;
    float acc = b3[q];
    #pragma unroll
    for (int p = 0; p < 8; ++p) {
      acc += o4[p*U2 + t    ] * w3[(q*8+p)*3 + 0]
           + o4[p*U2 + t + 1] * w3[(q*8+p)*3 + 1]
           + o4[p*U2 + t + 2] * w3[(q*8+p)*3 + 2];
    }
    o5[i2] = acc;
  }
  __syncthreads();
  // 256 threads: q = tid>>3 covers 0..31, vs = tid&7; v = vs + 8*i ascending
  // per thread; (max,min-idx) merge preserves first-max tie-break.
  // orow cached in registers: same 36 values reused across all 16 i-iters
  // (saves 540 ds_read_b32/thread; FP accumulation order unchanged).
  const int q = tid >> 3, vs = tid & 7;
  float orow_r[36];
  {
    const float* orow = &o5[q*T3];
    #pragma unroll
    for (int t = 0; t < 36; ++t) orow_r[t] = orow[t];
  }
  float best = -1e30f; int bidx = 0;
  for (int i = 0; i < 16; ++i) {
    int v = vs + 8*i;
    float acc = blb[v];
    const float* wr = &wlb[v*37];
    #pragma unroll
    for (int t = 0; t < 36; ++t) acc += orow_r[t] * wr[t];
    if (acc > best) { best = acc; bidx = v; }
  }
  #pragma unroll
  for (int off = 1; off < 8; off <<= 1) {
    float ov = __shfl_xor(best, off);
    int oi = __shfl_xor(bidx, off);
    if (ov > best || (ov == best && oi < bidx)) { best = ov; bidx = oi; }
  }
  if (vs == 0) out[s*BB + q] = (float)bidx;
}

extern "C" void kernel_launch(void* const* d_in, const int* in_sizes, int n_in,
                              void* d_out, int out_size, void* d_ws, size_t ws_size,
                              hipStream_t stream)
{
  const int*   tokens = (const int*)  d_in[0];
  const float* emb    = (const float*)d_in[1];
  const float* pos    = (const float*)d_in[2];
  const float* gamma  = (const float*)d_in[3];
  const float* beta   = (const float*)d_in[4];
  const float* w1     = (const float*)d_in[5];
  const float* b1     = (const float*)d_in[6];
  const float* w2     = (const float*)d_in[7];
  const float* b2     = (const float*)d_in[8];
  const float* w3     = (const float*)d_in[9];
  const float* b3     = (const float*)d_in[10];
  const float* wl     = (const float*)d_in[11];
  const float* bl     = (const float*)d_in[12];
  float* out = (float*)d_out;

  double* rowsumd = (double*)d_ws;            // 2048
  double* rowsqd  = rowsumd + NSTAT;          // 2048
  float*  part    = (float*)(rowsqd + NSTAT); // 4*64*16*114

  k_main<<<dim3(SS, 4), dim3(256), 0, stream>>>(
      tokens, emb, pos, w1, rowsumd, rowsqd, part);
  k_tail<<<dim3(SS), dim3(256), 0, stream>>>(
      rowsumd, rowsqd, gamma, beta, part, w1, b1, w2, b2, w3, b3,
      wl, bl, out);
}